// Round 7
// baseline (7912.970 us; speedup 1.0000x reference)
//
#include <hip/hip_runtime.h>
#include <math.h>

#define NB   512
#define TENC 128
#define FDEC 32
#define TTOT 160
#define HD   512

typedef short  short8  __attribute__((ext_vector_type(8)));
typedef float  f32x16  __attribute__((ext_vector_type(16)));

__device__ __forceinline__ unsigned short f2bf(float f) {
  unsigned u = __float_as_uint(f);
  u += 0x7FFFu + ((u >> 16) & 1u);          // RNE
  return (unsigned short)(u >> 16);
}
__device__ __forceinline__ float bf2f(unsigned short h) {
  return __uint_as_float(((unsigned)h) << 16);
}

__device__ __forceinline__ void gll16(const void* g, void* l) {
  __builtin_amdgcn_global_load_lds(
      (const __attribute__((address_space(1))) void*)g,
      (__attribute__((address_space(3))) void*)l, 16, 0, 0);
}

// ---------------------------------------------------------------------------
// Per-iteration staging: 6 gll16 per wave. Each wave stages ITS K-half (kh).
// Buffer layout (shorts), per khalf region of 6144:
//   A-hi [0,1024): unit (ks*2+kgrp)*32 + row(n 0..32)         -> 16B units
//   A-lo [1024,2048)
//   B-hi [2048,4096): unit (ks*2+kgrp)*64 + row(j 0..64)
//   B-lo [4096,6144)
// parity 0 waves stage A-hi/A-lo + B-hi units 0..127;
// parity 1 waves stage B-hi units 128..255 + all B-lo.
// Sources: aHp/aLp pre-offset to (n0+lan)*HD + khalf-k-base;
//          bHp/bLp pre-offset to (j0+l)*LDK + khalf-k-base.
// ---------------------------------------------------------------------------
__device__ __forceinline__ void stage6(short* db, int par,
    const unsigned short* aHp, const unsigned short* aLp,
    const unsigned short* bHp, const unsigned short* bLp,
    int kb, int agrp)
{
  if (par == 0) {
    gll16(aHp + kb + agrp,      db);
    gll16(aHp + kb + agrp + 16, db + 512);
    gll16(aLp + kb + agrp,      db + 1024);
    gll16(aLp + kb + agrp + 16, db + 1536);
    gll16(bHp + kb,             db + 2048);
    gll16(bHp + kb + 8,         db + 2560);
  } else {
    gll16(bHp + kb + 16,        db + 3072);
    gll16(bHp + kb + 24,        db + 3584);
    gll16(bLp + kb,             db + 4096);
    gll16(bLp + kb + 8,         db + 4608);
    gll16(bLp + kb + 16,        db + 5120);
    gll16(bLp + kb + 24,        db + 5632);
  }
}

// one 32-wide k slice of this wave's K-half: 2 ksub x 3 compensated MFMAs
__device__ __forceinline__ void compute6(const short* base, int aoff, int boff,
                                         f32x16& acc) {
#pragma unroll
  for (int ks = 0; ks < 2; ++ks) {
    const short* pa = base + aoff + ks * 512;
    const short* pb = base + boff + ks * 1024;
    short8 ah = *(const short8*)(pa);
    short8 al = *(const short8*)(pa + 1024);
    short8 bh = *(const short8*)(pb);
    short8 bl = *(const short8*)(pb + 2048);
    acc = __builtin_amdgcn_mfma_f32_32x32x16_bf16(ah, bh, acc, 0, 0, 0);
    acc = __builtin_amdgcn_mfma_f32_32x32x16_bf16(ah, bl, acc, 0, 0, 0);
    acc = __builtin_amdgcn_mfma_f32_32x32x16_bf16(al, bh, acc, 0, 0, 0);
  }
}

// ---------------------------------------------------------------------------
// split weights into hi/lo bf16, rows permuted to j = d*4 + gate.
// W1 (from Whh1): [2048][512].  W2cat (Wih2|Whh2): [2048][1024].
// ---------------------------------------------------------------------------
__global__ __launch_bounds__(256) void split_w(
    const float* __restrict__ Whh1, const float* __restrict__ Wih2,
    const float* __restrict__ Whh2,
    unsigned short* __restrict__ W1h, unsigned short* __restrict__ W1l,
    unsigned short* __restrict__ W2h, unsigned short* __restrict__ W2l)
{
  int idx = blockIdx.x * 256 + threadIdx.x;
  if (idx < 2048 * 64) {
    int j = idx >> 6, kg = (idx & 63) << 3;
    const float* s = Whh1 + (size_t)((j & 3) * HD + (j >> 2)) * HD + kg;
    unsigned short* oh = W1h + (size_t)j * HD + kg;
    unsigned short* ol = W1l + (size_t)j * HD + kg;
#pragma unroll
    for (int i = 0; i < 8; ++i) {
      float v = s[i];
      unsigned short h = f2bf(v);
      oh[i] = h; ol[i] = f2bf(v - bf2f(h));
    }
  } else {
    int q = idx - 2048 * 64;
    if (q >= 2048 * 128) return;
    int j = q >> 7, kg = (q & 127) << 3;
    int srow = (j & 3) * HD + (j >> 2);
    const float* s = (kg < 512) ? (Wih2 + (size_t)srow * HD + kg)
                                : (Whh2 + (size_t)srow * HD + (kg - 512));
    unsigned short* oh = W2h + (size_t)j * 1024 + kg;
    unsigned short* ol = W2l + (size_t)j * 1024 + kg;
#pragma unroll
    for (int i = 0; i < 8; ++i) {
      float v = s[i];
      unsigned short h = f2bf(v);
      oh[i] = h; ol[i] = f2bf(v - bf2f(h));
    }
  }
}

// ---------------------------------------------------------------------------
// Layer-1 step. Block tile: 64 j x 32 n, 4 waves: wave=(kh=K-half, jh=j-half).
// Grid (32 j, 16 n) = 512 blocks = 2/CU. K=512 -> 8 iters of (2 x 32k).
// ---------------------------------------------------------------------------
__global__ __launch_bounds__(256, 2) void lstm1_step(
    const unsigned short* __restrict__ hinH, const unsigned short* __restrict__ hinL,
    unsigned short* __restrict__ houtH, unsigned short* __restrict__ houtL,
    float* __restrict__ c1,
    const unsigned short* __restrict__ WH, const unsigned short* __restrict__ WL,
    const float* __restrict__ Wih, const float* __restrict__ bih,
    const float* __restrict__ bhh,
    const float* __restrict__ x, const float* __restrict__ tgt,
    const int* __restrict__ tfm, const float* __restrict__ outp, int t)
{
  __shared__ short lds[3 * 12288];     // 72 KB
  const int tid = threadIdx.x;
  const int w = tid >> 6, l = tid & 63;
  const int kh = w >> 1, jh = w & 1;
  const int lan = l & 31, kgq = l >> 5;
  const int j0 = blockIdx.x * 64;
  const int n0 = blockIdx.y * 32;

  const unsigned short* aHp = hinH + (size_t)(n0 + lan) * HD + kh * 256;
  const unsigned short* aLp = hinL + (size_t)(n0 + lan) * HD + kh * 256;
  const unsigned short* bHp = WH + (size_t)(j0 + l) * 512 + kh * 256;
  const unsigned short* bLp = WL + (size_t)(j0 + l) * 512 + kh * 256;
  const int agrp = kgq * 8;
  const int aoff = (kgq * 32 + lan) * 8;
  const int boff = 2048 + (kgq * 64 + jh * 32 + lan) * 8;
  short* db0 = lds + kh * 6144;

  f32x16 acc;
#pragma unroll
  for (int r = 0; r < 16; ++r) acc[r] = 0.f;

  stage6(db0,         jh, aHp, aLp, bHp, bLp, 0,  agrp);
  stage6(db0 + 12288, jh, aHp, aLp, bHp, bLp, 32, agrp);
  asm volatile("s_waitcnt vmcnt(6)" ::: "memory");
  __builtin_amdgcn_s_barrier();
  __builtin_amdgcn_sched_barrier(0);

  for (int c = 0; c < 8; ++c) {
    if (c + 2 < 8)
      stage6(lds + ((c + 2) % 3) * 12288 + kh * 6144, jh,
             aHp, aLp, bHp, bLp, (c + 2) * 32, agrp);
    compute6(lds + (c % 3) * 12288 + kh * 6144, aoff, boff, acc);
    if (c + 1 < 8) {
      if (c + 2 < 8) asm volatile("s_waitcnt vmcnt(6)" ::: "memory");
      else           asm volatile("s_waitcnt vmcnt(0)" ::: "memory");
      __builtin_amdgcn_s_barrier();
      __builtin_amdgcn_sched_barrier(0);
    }
  }
  __syncthreads();

  // exchange: Gs[kh][j_loc 64][n 32 +pad2]; K-half partials summed on read
  float* Gs = (float*)lds;
#pragma unroll
  for (int r = 0; r < 16; ++r) {
    int nrow = (r & 3) + 8 * (r >> 2) + 4 * kgq;
    Gs[(kh * 64 + jh * 32 + lan) * 34 + nrow] = acc[r];
  }
  __syncthreads();

  const int dl = tid & 15, q = tid >> 4;
  const int dg = blockIdx.x * 16 + dl;
  float wi[4], bsum[4];
#pragma unroll
  for (int g4 = 0; g4 < 4; ++g4) {
    int row = g4 * HD + dg;
    wi[g4] = Wih[row];
    bsum[g4] = bih[row] + bhh[row];
  }
#pragma unroll
  for (int s = 0; s < 2; ++s) {
    int nloc = q * 2 + s, n = n0 + nloc;
    float xv;
    if (t < TENC) xv = x[n * TENC + t];
    else {
      int j2 = t - TENC;
      xv = (tfm[j2] > 0) ? tgt[n * FDEC + j2] : outp[n * TTOT + t - 1];
    }
    float p[4];
#pragma unroll
    for (int g4 = 0; g4 < 4; ++g4)
      p[g4] = Gs[(dl * 4 + g4) * 34 + nloc] + Gs[(64 + dl * 4 + g4) * 34 + nloc]
            + xv * wi[g4] + bsum[g4];
    float ig = 1.f / (1.f + expf(-p[0]));
    float fg = 1.f / (1.f + expf(-p[1]));
    float gv = tanhf(p[2]);
    float og = 1.f / (1.f + expf(-p[3]));
    int idx = n * HD + dg;
    float c = fg * c1[idx] + ig * gv;
    c1[idx] = c;
    float h = og * tanhf(c);
    unsigned short hh = f2bf(h);
    houtH[idx] = hh;
    houtL[idx] = f2bf(h - bf2f(hh));
  }
}

// ---------------------------------------------------------------------------
// Layer-2 step. K=1024: K-half 0 = h1 (current), K-half 1 = h2 (prev).
// 16 iters. Cell + FC partial reduce + atomicAdd.
// ---------------------------------------------------------------------------
__global__ __launch_bounds__(256, 2) void lstm2_step(
    const unsigned short* __restrict__ a1H, const unsigned short* __restrict__ a1L,
    const unsigned short* __restrict__ a2H, const unsigned short* __restrict__ a2L,
    unsigned short* __restrict__ houtH, unsigned short* __restrict__ houtL,
    float* __restrict__ c2,
    const unsigned short* __restrict__ WH, const unsigned short* __restrict__ WL,
    const float* __restrict__ bih, const float* __restrict__ bhh,
    const float* __restrict__ wfc, const float* __restrict__ bfc,
    float* __restrict__ outp, int t)
{
  __shared__ short lds[3 * 12288];
  const int tid = threadIdx.x;
  const int w = tid >> 6, l = tid & 63;
  const int kh = w >> 1, jh = w & 1;
  const int lan = l & 31, kgq = l >> 5;
  const int j0 = blockIdx.x * 64;
  const int n0 = blockIdx.y * 32;

  const unsigned short* aHp = (kh ? a2H : a1H) + (size_t)(n0 + lan) * HD;
  const unsigned short* aLp = (kh ? a2L : a1L) + (size_t)(n0 + lan) * HD;
  const unsigned short* bHp = WH + (size_t)(j0 + l) * 1024 + kh * 512;
  const unsigned short* bLp = WL + (size_t)(j0 + l) * 1024 + kh * 512;
  const int agrp = kgq * 8;
  const int aoff = (kgq * 32 + lan) * 8;
  const int boff = 2048 + (kgq * 64 + jh * 32 + lan) * 8;
  short* db0 = lds + kh * 6144;

  f32x16 acc;
#pragma unroll
  for (int r = 0; r < 16; ++r) acc[r] = 0.f;

  stage6(db0,         jh, aHp, aLp, bHp, bLp, 0,  agrp);
  stage6(db0 + 12288, jh, aHp, aLp, bHp, bLp, 32, agrp);
  asm volatile("s_waitcnt vmcnt(6)" ::: "memory");
  __builtin_amdgcn_s_barrier();
  __builtin_amdgcn_sched_barrier(0);

  for (int c = 0; c < 16; ++c) {
    if (c + 2 < 16)
      stage6(lds + ((c + 2) % 3) * 12288 + kh * 6144, jh,
             aHp, aLp, bHp, bLp, (c + 2) * 32, agrp);
    compute6(lds + (c % 3) * 12288 + kh * 6144, aoff, boff, acc);
    if (c + 1 < 16) {
      if (c + 2 < 16) asm volatile("s_waitcnt vmcnt(6)" ::: "memory");
      else            asm volatile("s_waitcnt vmcnt(0)" ::: "memory");
      __builtin_amdgcn_s_barrier();
      __builtin_amdgcn_sched_barrier(0);
    }
  }
  __syncthreads();

  float* Gs = (float*)lds;                  // [2][64][34]
  float* Rd = (float*)lds + 2 * 64 * 34;    // [32][17]
#pragma unroll
  for (int r = 0; r < 16; ++r) {
    int nrow = (r & 3) + 8 * (r >> 2) + 4 * kgq;
    Gs[(kh * 64 + jh * 32 + lan) * 34 + nrow] = acc[r];
  }
  __syncthreads();

  const int dl = tid & 15, q = tid >> 4;
  const int dg = blockIdx.x * 16 + dl;
  float bsum[4];
#pragma unroll
  for (int g4 = 0; g4 < 4; ++g4) bsum[g4] = bih[g4 * HD + dg] + bhh[g4 * HD + dg];
  const float wf = wfc[dg];
#pragma unroll
  for (int s = 0; s < 2; ++s) {
    int nloc = q * 2 + s, n = n0 + nloc;
    float p[4];
#pragma unroll
    for (int g4 = 0; g4 < 4; ++g4)
      p[g4] = Gs[(dl * 4 + g4) * 34 + nloc] + Gs[(64 + dl * 4 + g4) * 34 + nloc]
            + bsum[g4];
    float ig = 1.f / (1.f + expf(-p[0]));
    float fg = 1.f / (1.f + expf(-p[1]));
    float gv = tanhf(p[2]);
    float og = 1.f / (1.f + expf(-p[3]));
    int idx = n * HD + dg;
    float c = fg * c2[idx] + ig * gv;
    c2[idx] = c;
    float h = og * tanhf(c);
    unsigned short hh = f2bf(h);
    houtH[idx] = hh;
    houtL[idx] = f2bf(h - bf2f(hh));
    Rd[nloc * 17 + dl] = h * wf;
  }
  __syncthreads();
  if (tid < 32) {
    float sum = 0.f;
#pragma unroll
    for (int k = 0; k < 16; ++k) sum += Rd[tid * 17 + k];
    if (blockIdx.x == 0) sum += bfc[0];
    atomicAdd(&outp[(n0 + tid) * TTOT + t], sum);
  }
}

// ---------------------------------------------------------------------------
extern "C" void kernel_launch(void* const* d_in, const int* in_sizes, int n_in,
                              void* d_out, int out_size, void* d_ws, size_t ws_size,
                              hipStream_t stream)
{
  const float* x    = (const float*)d_in[0];
  const float* tgt  = (const float*)d_in[1];
  const int*   tfm  = (const int*)  d_in[2];
  const float* Wih1 = (const float*)d_in[4];
  const float* Whh1 = (const float*)d_in[5];
  const float* bih1 = (const float*)d_in[6];
  const float* bhh1 = (const float*)d_in[7];
  const float* Wih2 = (const float*)d_in[8];
  const float* Whh2 = (const float*)d_in[9];
  const float* bih2 = (const float*)d_in[10];
  const float* bhh2 = (const float*)d_in[11];
  const float* wfc  = (const float*)d_in[12];
  const float* bfc  = (const float*)d_in[13];
  float* outp = (float*)d_out;

  const size_t W1E = 2048 * 512, W2E = 2048 * 1024, HE = 512 * 512;
  unsigned short* W1h = (unsigned short*)d_ws;
  unsigned short* W1l = W1h + W1E;
  unsigned short* W2h = W1l + W1E;
  unsigned short* W2l = W2h + W2E;
  unsigned short* h1H = W2l + W2E;          // [2][HE]
  unsigned short* h1L = h1H + 2 * HE;
  unsigned short* h2H = h1L + 2 * HE;
  unsigned short* h2L = h2H + 2 * HE;
  float* c1 = (float*)(h2L + 2 * HE);
  float* c2 = c1 + HE;

  hipMemsetAsync(h1H, 0, 8 * HE * sizeof(unsigned short) + 2 * HE * sizeof(float), stream);
  hipMemsetAsync(d_out, 0, (size_t)NB * TTOT * sizeof(float), stream);

  split_w<<<1536, 256, 0, stream>>>(Whh1, Wih2, Whh2, W1h, W1l, W2h, W2l);

  dim3 grid(32, 16), blk(256);
  for (int t = 0; t < TTOT; ++t) {
    int p = t & 1;
    lstm1_step<<<grid, blk, 0, stream>>>(
        h1H + p * HE, h1L + p * HE, h1H + (p ^ 1) * HE, h1L + (p ^ 1) * HE,
        c1, W1h, W1l, Wih1, bih1, bhh1, x, tgt, tfm, outp, t);
    lstm2_step<<<grid, blk, 0, stream>>>(
        h1H + (p ^ 1) * HE, h1L + (p ^ 1) * HE, h2H + p * HE, h2L + p * HE,
        h2H + (p ^ 1) * HE, h2L + (p ^ 1) * HE,
        c2, W2h, W2l, bih2, bhh2, wfc, bfc, outp, t);
  }
}

// Round 8
// 6472.129 us; speedup vs baseline: 1.2226x; 1.2226x over previous
//
#include <hip/hip_runtime.h>
#include <math.h>

#define NB   512
#define TENC 128
#define FDEC 32
#define TTOT 160
#define HD   512

typedef short  short8  __attribute__((ext_vector_type(8)));
typedef float  f32x16  __attribute__((ext_vector_type(16)));

__device__ __forceinline__ unsigned short f2bf(float f) {
  unsigned u = __float_as_uint(f);
  u += 0x7FFFu + ((u >> 16) & 1u);          // RNE
  return (unsigned short)(u >> 16);
}
__device__ __forceinline__ float bf2f(unsigned short h) {
  return __uint_as_float(((unsigned)h) << 16);
}

__device__ __forceinline__ void gll16(const void* g, void* l) {
  __builtin_amdgcn_global_load_lds(
      (const __attribute__((address_space(1))) void*)g,
      (__attribute__((address_space(3))) void*)l, 16, 0, 0);
}

// ---------------------------------------------------------------------------
// Pre-pack weights into fragment-major blocks so kernel staging is fully
// coalesced (lane i reads base + i*16B) and LDS needs no swizzle.
// W1p: 32 j-blocks(64 j) x [hi 4096 units | lo 4096 units], unit(16B) index
//      u = (c*2+ks)*128 + kgrp*64 + jl   (c: k-chunk of 32, ks: 16-half,
//      kgrp: 8-group = MFMA lane>>5, jl: j within block), j = d*4+gate.
// W2p: 64 j-blocks(32 j) x same structure with u = (c*2+ks)*64 + kgrp*32 + jl,
//      K=1024 = [Wih2 | Whh2].
// ---------------------------------------------------------------------------
__global__ __launch_bounds__(256) void split_w(
    const float* __restrict__ Whh1, const float* __restrict__ Wih2,
    const float* __restrict__ Whh2,
    unsigned short* __restrict__ W1p, unsigned short* __restrict__ W2p)
{
  int idx = blockIdx.x * 256 + threadIdx.x;      // 393216 threads
  if (idx < 131072) {                            // W1: 32 J x 4096 units
    int J = idx >> 12, u = idx & 4095;
    int cks  = u >> 7;                           // c*2+ks in [0,32)
    int kgrp = (u >> 6) & 1;
    int jl   = u & 63;
    int j = J * 64 + jl;
    int k = (cks >> 1) * 32 + (cks & 1) * 16 + kgrp * 8;
    int g = j & 3, d = j >> 2;
    const float* s = Whh1 + (size_t)(g * HD + d) * HD + k;
    unsigned short* oh = W1p + (size_t)J * 65536 + (size_t)u * 8;
    unsigned short* ol = oh + 32768;
#pragma unroll
    for (int i = 0; i < 8; ++i) {
      float v = s[i];
      unsigned short h = f2bf(v);
      oh[i] = h; ol[i] = f2bf(v - bf2f(h));
    }
  } else {                                       // W2: 64 J x 4096 units
    int q2 = idx - 131072;
    int J = q2 >> 12, u = q2 & 4095;
    int cks  = u >> 6;                           // c*2+ks in [0,64)
    int kgrp = (u >> 5) & 1;
    int jl   = u & 31;
    int j = J * 32 + jl;
    int k = (cks >> 1) * 32 + (cks & 1) * 16 + kgrp * 8;   // [0,1024)
    int g = j & 3, d = j >> 2;
    const float* s = (k < 512) ? (Wih2 + (size_t)(g * HD + d) * HD + k)
                               : (Whh2 + (size_t)(g * HD + d) * HD + (k - 512));
    unsigned short* oh = W2p + (size_t)J * 65536 + (size_t)u * 8;
    unsigned short* ol = oh + 32768;
#pragma unroll
    for (int i = 0; i < 8; ++i) {
      float v = s[i];
      unsigned short h = f2bf(v);
      oh[i] = h; ol[i] = f2bf(v - bf2f(h));
    }
  }
}

// ---------------------------------------------------------------------------
// Layer-1 step. Tile 64j x 64n, 4 waves (2j x 2n), grid (32,8)=256 blocks.
// B (W1 slice, 128 KB) resident in LDS, staged once, coalesced. A (h) loaded
// direct global->VGPR per chunk (16B/lane, full 64B rows consumed). K-loop:
// 16 chunks x 6 MFMA, NO barriers.
// ---------------------------------------------------------------------------
__global__ __launch_bounds__(256) void lstm1_step(
    const unsigned short* __restrict__ hinH, const unsigned short* __restrict__ hinL,
    unsigned short* __restrict__ houtH, unsigned short* __restrict__ houtL,
    float* __restrict__ c1,
    const unsigned short* __restrict__ W1p,
    const float* __restrict__ Wih, const float* __restrict__ bih,
    const float* __restrict__ bhh,
    const float* __restrict__ x, const float* __restrict__ tgt,
    const int* __restrict__ tfm, const float* __restrict__ outp, int t)
{
  __shared__ unsigned short Bs[65536];     // 128 KB: hi [0,32768), lo [32768,)
  __shared__ float Gs[64 * 66];            // gate exchange
  const int tid = threadIdx.x;
  const int w = tid >> 6, l = tid & 63;
  const int jh = w >> 1, nh = w & 1;
  const int lan = l & 31, kgq = l >> 5;
  const int n0 = blockIdx.y * 64;
  const int J = blockIdx.x;

  // coalesced one-shot B staging: 32 x 1KB segments per wave
  const unsigned short* wsrc = W1p + (size_t)J * 65536 + (size_t)l * 8;
#pragma unroll
  for (int r = 0; r < 32; ++r) {
    int s = r * 4 + w;
    gll16(wsrc + (size_t)s * 512, Bs + s * 512);
  }

  const unsigned short* aH = hinH + (size_t)(n0 + nh * 32 + lan) * HD + kgq * 8;
  const unsigned short* aL = hinL + (size_t)(n0 + nh * 32 + lan) * HD + kgq * 8;

  f32x16 acc;
#pragma unroll
  for (int r = 0; r < 16; ++r) acc[r] = 0.f;

  __syncthreads();                         // drain gll + barrier (once)

#pragma unroll
  for (int c = 0; c < 16; ++c) {
#pragma unroll
    for (int ks = 0; ks < 2; ++ks) {
      int ka = c * 32 + ks * 16;
      short8 ah = *(const short8*)(aH + ka);
      short8 al = *(const short8*)(aL + ka);
      int ub = ((c * 2 + ks) * 128 + kgq * 64 + jh * 32 + lan) * 8;
      short8 bh = *(const short8*)((const short*)Bs + ub);
      short8 bl = *(const short8*)((const short*)Bs + ub + 32768);
      acc = __builtin_amdgcn_mfma_f32_32x32x16_bf16(ah, bh, acc, 0, 0, 0);
      acc = __builtin_amdgcn_mfma_f32_32x32x16_bf16(ah, bl, acc, 0, 0, 0);
      acc = __builtin_amdgcn_mfma_f32_32x32x16_bf16(al, bh, acc, 0, 0, 0);
    }
  }

  // gate exchange: Gs[j_local][n_local]
#pragma unroll
  for (int r = 0; r < 16; ++r) {
    int nrow = (r & 3) + 8 * (r >> 2) + 4 * kgq;
    Gs[(jh * 32 + lan) * 66 + nh * 32 + nrow] = acc[r];
  }
  __syncthreads();

  const int dl = tid & 15, q = tid >> 4;
  const int dg = blockIdx.x * 16 + dl;
  float wi[4], bsum[4];
#pragma unroll
  for (int g4 = 0; g4 < 4; ++g4) {
    int row = g4 * HD + dg;
    wi[g4] = Wih[row];
    bsum[g4] = bih[row] + bhh[row];
  }
#pragma unroll
  for (int jj = 0; jj < 4; ++jj) {
    int nloc = q * 4 + jj, n = n0 + nloc;
    float xv;
    if (t < TENC) xv = x[n * TENC + t];
    else {
      int j2 = t - TENC;
      xv = (tfm[j2] > 0) ? tgt[n * FDEC + j2] : outp[n * TTOT + t - 1];
    }
    float p[4];
#pragma unroll
    for (int g4 = 0; g4 < 4; ++g4)
      p[g4] = Gs[(dl * 4 + g4) * 66 + nloc] + xv * wi[g4] + bsum[g4];
    float ig = 1.f / (1.f + expf(-p[0]));
    float fg = 1.f / (1.f + expf(-p[1]));
    float gv = tanhf(p[2]);
    float og = 1.f / (1.f + expf(-p[3]));
    int idx = n * HD + dg;
    float c = fg * c1[idx] + ig * gv;
    c1[idx] = c;
    float h = og * tanhf(c);
    unsigned short hh = f2bf(h);
    houtH[idx] = hh;
    houtL[idx] = f2bf(h - bf2f(hh));
  }
}

// ---------------------------------------------------------------------------
// Layer-2 step. Tile 32j x 128n, 4 waves (4 n-quarters), grid (64,4)=256.
// B (W2 slice, 128 KB) resident; A = [h1 cur | h2 prev] direct loads.
// 32 chunks x 6 MFMA, no barriers. Cell + FC partial + atomicAdd.
// ---------------------------------------------------------------------------
__global__ __launch_bounds__(256) void lstm2_step(
    const unsigned short* __restrict__ a1H, const unsigned short* __restrict__ a1L,
    const unsigned short* __restrict__ a2H, const unsigned short* __restrict__ a2L,
    unsigned short* __restrict__ houtH, unsigned short* __restrict__ houtL,
    float* __restrict__ c2,
    const unsigned short* __restrict__ W2p,
    const float* __restrict__ bih, const float* __restrict__ bhh,
    const float* __restrict__ wfc, const float* __restrict__ bfc,
    float* __restrict__ outp, int t)
{
  __shared__ unsigned short Bs[65536];     // 128 KB
  __shared__ float Gs[32 * 130];
  __shared__ float Rd[128 * 9];
  const int tid = threadIdx.x;
  const int w = tid >> 6, l = tid & 63;
  const int lan = l & 31, kgq = l >> 5;
  const int J = blockIdx.x;                // 64 j-blocks of 32 j
  const int n0 = blockIdx.y * 128;

  const unsigned short* wsrc = W2p + (size_t)J * 65536 + (size_t)l * 8;
#pragma unroll
  for (int r = 0; r < 32; ++r) {
    int s = r * 4 + w;
    gll16(wsrc + (size_t)s * 512, Bs + s * 512);
  }

  const size_t arow = (size_t)(n0 + w * 32 + lan) * HD + kgq * 8;
  const unsigned short* p1H = a1H + arow;
  const unsigned short* p1L = a1L + arow;
  const unsigned short* p2H = a2H + arow;
  const unsigned short* p2L = a2L + arow;

  f32x16 acc;
#pragma unroll
  for (int r = 0; r < 16; ++r) acc[r] = 0.f;

  __syncthreads();

#pragma unroll
  for (int c = 0; c < 32; ++c) {
#pragma unroll
    for (int ks = 0; ks < 2; ++ks) {
      int kk = c * 32 + ks * 16;
      short8 ah = (kk < 512) ? *(const short8*)(p1H + kk)
                             : *(const short8*)(p2H + kk - 512);
      short8 al = (kk < 512) ? *(const short8*)(p1L + kk)
                             : *(const short8*)(p2L + kk - 512);
      int ub = ((c * 2 + ks) * 64 + kgq * 32 + lan) * 8;
      short8 bh = *(const short8*)((const short*)Bs + ub);
      short8 bl = *(const short8*)((const short*)Bs + ub + 32768);
      acc = __builtin_amdgcn_mfma_f32_32x32x16_bf16(ah, bh, acc, 0, 0, 0);
      acc = __builtin_amdgcn_mfma_f32_32x32x16_bf16(ah, bl, acc, 0, 0, 0);
      acc = __builtin_amdgcn_mfma_f32_32x32x16_bf16(al, bh, acc, 0, 0, 0);
    }
  }

#pragma unroll
  for (int r = 0; r < 16; ++r) {
    int nrow = (r & 3) + 8 * (r >> 2) + 4 * kgq;
    Gs[lan * 130 + w * 32 + nrow] = acc[r];
  }
  __syncthreads();

  const int dl = tid & 7, q = tid >> 3;        // 8 d x 32 n-groups
  const int dg = J * 8 + dl;
  float bsum[4];
#pragma unroll
  for (int g4 = 0; g4 < 4; ++g4) bsum[g4] = bih[g4 * HD + dg] + bhh[g4 * HD + dg];
  const float wf = wfc[dg];
#pragma unroll
  for (int s = 0; s < 4; ++s) {
    int nloc = q * 4 + s, n = n0 + nloc;
    float p[4];
#pragma unroll
    for (int g4 = 0; g4 < 4; ++g4)
      p[g4] = Gs[(dl * 4 + g4) * 130 + nloc] + bsum[g4];
    float ig = 1.f / (1.f + expf(-p[0]));
    float fg = 1.f / (1.f + expf(-p[1]));
    float gv = tanhf(p[2]);
    float og = 1.f / (1.f + expf(-p[3]));
    int idx = n * HD + dg;
    float c = fg * c2[idx] + ig * gv;
    c2[idx] = c;
    float h = og * tanhf(c);
    unsigned short hh = f2bf(h);
    houtH[idx] = hh;
    houtL[idx] = f2bf(h - bf2f(hh));
    Rd[nloc * 9 + dl] = h * wf;
  }
  __syncthreads();
  if (tid < 128) {
    float sum = 0.f;
#pragma unroll
    for (int k = 0; k < 8; ++k) sum += Rd[tid * 9 + k];
    if (J == 0) sum += bfc[0];
    atomicAdd(&outp[(n0 + tid) * TTOT + t], sum);
  }
}

// ---------------------------------------------------------------------------
extern "C" void kernel_launch(void* const* d_in, const int* in_sizes, int n_in,
                              void* d_out, int out_size, void* d_ws, size_t ws_size,
                              hipStream_t stream)
{
  const float* x    = (const float*)d_in[0];
  const float* tgt  = (const float*)d_in[1];
  const int*   tfm  = (const int*)  d_in[2];
  const float* Wih1 = (const float*)d_in[4];
  const float* Whh1 = (const float*)d_in[5];
  const float* bih1 = (const float*)d_in[6];
  const float* bhh1 = (const float*)d_in[7];
  const float* Wih2 = (const float*)d_in[8];
  const float* Whh2 = (const float*)d_in[9];
  const float* bih2 = (const float*)d_in[10];
  const float* bhh2 = (const float*)d_in[11];
  const float* wfc  = (const float*)d_in[12];
  const float* bfc  = (const float*)d_in[13];
  float* outp = (float*)d_out;

  const size_t W1E = 32 * 65536;            // 2,097,152 shorts (4 MB)
  const size_t W2E = 64 * 65536;            // 4,194,304 shorts (8 MB)
  const size_t HE  = 512 * 512;
  unsigned short* W1p = (unsigned short*)d_ws;
  unsigned short* W2p = W1p + W1E;
  unsigned short* h1H = W2p + W2E;          // [2][HE]
  unsigned short* h1L = h1H + 2 * HE;
  unsigned short* h2H = h1L + 2 * HE;
  unsigned short* h2L = h2H + 2 * HE;
  float* c1 = (float*)(h2L + 2 * HE);
  float* c2 = c1 + HE;

  hipMemsetAsync(h1H, 0, 8 * HE * sizeof(unsigned short) + 2 * HE * sizeof(float), stream);
  hipMemsetAsync(d_out, 0, (size_t)NB * TTOT * sizeof(float), stream);

  split_w<<<1536, 256, 0, stream>>>(Whh1, Wih2, Whh2, W1p, W2p);

  dim3 blk(256), g1(32, 8), g2(64, 4);
  for (int t = 0; t < TTOT; ++t) {
    int p = t & 1;
    lstm1_step<<<g1, blk, 0, stream>>>(
        h1H + p * HE, h1L + p * HE, h1H + (p ^ 1) * HE, h1L + (p ^ 1) * HE,
        c1, W1p, Wih1, bih1, bhh1, x, tgt, tfm, outp, t);
    lstm2_step<<<g2, blk, 0, stream>>>(
        h1H + (p ^ 1) * HE, h1L + (p ^ 1) * HE, h2H + p * HE, h2L + p * HE,
        h2H + (p ^ 1) * HE, h2L + (p ^ 1) * HE,
        c2, W2p, bih2, bhh2, wfc, bfc, outp, t);
  }
}

// Round 9
// 4362.420 us; speedup vs baseline: 1.8139x; 1.4836x over previous
//
#include <hip/hip_runtime.h>
#include <math.h>

#define NB   512
#define TENC 128
#define FDEC 32
#define TTOT 160
#define HD   512

typedef short  short8  __attribute__((ext_vector_type(8)));
typedef float  f32x16  __attribute__((ext_vector_type(16)));

__device__ __forceinline__ unsigned short f2bf(float f) {
  unsigned u = __float_as_uint(f);
  u += 0x7FFFu + ((u >> 16) & 1u);          // RNE
  return (unsigned short)(u >> 16);
}
__device__ __forceinline__ float bf2f(unsigned short h) {
  return __uint_as_float(((unsigned)h) << 16);
}

__device__ __forceinline__ void gll16(const void* g, void* l) {
  __builtin_amdgcn_global_load_lds(
      (const __attribute__((address_space(1))) void*)g,
      (__attribute__((address_space(3))) void*)l, 16, 0, 0);
}

// packed-h short index for element (n, d): 32-row n-blocks, fragment-major.
// unit u = (c*2+ks)*64 + kq*32 + lan ; c=d>>5, ks=(d>>4)&1, kq=(d>>3)&1.
__device__ __forceinline__ size_t hpk(int n, int d) {
  int nblk = n >> 5, lanw = n & 31;
  int cks = (d >> 4);                       // (c*2+ks)
  int kq  = (d >> 3) & 1;
  return (size_t)nblk * 16384 +
         (size_t)(((cks * 64 + kq * 32 + lanw) << 3) + (d & 7));
}

// ---------------------------------------------------------------------------
// Pre-pack weights fragment-major (identical to round 8):
// W1p: 32 J-blocks(64 j) x [hi 4096 u | lo 4096 u], u = cks*128 + kgrp*64 + jl
// W2p: 64 J-blocks(32 j) x [hi | lo],               u = cks*64  + kgrp*32 + jl
// j = d*4 + gate; K2 = [Wih2 | Whh2].
// ---------------------------------------------------------------------------
__global__ __launch_bounds__(256) void split_w(
    const float* __restrict__ Whh1, const float* __restrict__ Wih2,
    const float* __restrict__ Whh2,
    unsigned short* __restrict__ W1p, unsigned short* __restrict__ W2p)
{
  int idx = blockIdx.x * 256 + threadIdx.x;      // 393216 threads
  if (idx < 131072) {                            // W1: 32 J x 4096 units
    int J = idx >> 12, u = idx & 4095;
    int cks  = u >> 7;
    int kgrp = (u >> 6) & 1;
    int jl   = u & 63;
    int j = J * 64 + jl;
    int k = (cks >> 1) * 32 + (cks & 1) * 16 + kgrp * 8;
    int g = j & 3, d = j >> 2;
    const float* s = Whh1 + (size_t)(g * HD + d) * HD + k;
    unsigned short* oh = W1p + (size_t)J * 65536 + (size_t)u * 8;
    unsigned short* ol = oh + 32768;
#pragma unroll
    for (int i = 0; i < 8; ++i) {
      float v = s[i];
      unsigned short h = f2bf(v);
      oh[i] = h; ol[i] = f2bf(v - bf2f(h));
    }
  } else {                                       // W2: 64 J x 4096 units
    int q2 = idx - 131072;
    int J = q2 >> 12, u = q2 & 4095;
    int cks  = u >> 6;
    int kgrp = (u >> 5) & 1;
    int jl   = u & 31;
    int j = J * 32 + jl;
    int k = (cks >> 1) * 32 + (cks & 1) * 16 + kgrp * 8;   // [0,1024)
    int g = j & 3, d = j >> 2;
    const float* s = (k < 512) ? (Wih2 + (size_t)(g * HD + d) * HD + k)
                               : (Whh2 + (size_t)(g * HD + d) * HD + (k - 512));
    unsigned short* oh = W2p + (size_t)J * 65536 + (size_t)u * 8;
    unsigned short* ol = oh + 32768;
#pragma unroll
    for (int i = 0; i < 8; ++i) {
      float v = s[i];
      unsigned short h = f2bf(v);
      oh[i] = h; ol[i] = f2bf(v - bf2f(h));
    }
  }
}

// ---------------------------------------------------------------------------
// Layer-1 step. Tile 64j x 64n, 8 waves = (kh K-half, jh j-half, nh n-half).
// Grid (32 J, 8 ny) = 256 blocks, 512 thr, LDS 128 KB -> 2 waves/SIMD.
// B resident (one coalesced stage), A packed fragment-major (coalesced).
// K-loop barrier-free; kh partials combined in aliased Gs.
// ---------------------------------------------------------------------------
__global__ __launch_bounds__(512, 2) void lstm1_step(
    const unsigned short* __restrict__ hinH, const unsigned short* __restrict__ hinL,
    unsigned short* __restrict__ houtH, unsigned short* __restrict__ houtL,
    float* __restrict__ c1,
    const unsigned short* __restrict__ W1p,
    const float* __restrict__ Wih, const float* __restrict__ bih,
    const float* __restrict__ bhh,
    const float* __restrict__ x, const float* __restrict__ tgt,
    const int* __restrict__ tfm, const float* __restrict__ outp, int t)
{
  __shared__ unsigned short Bs[65536];     // 128 KB; Gs aliases after K-loop
  const int tid = threadIdx.x;
  const int w = tid >> 6, l = tid & 63;
  const int kh = w >> 2, jh = (w >> 1) & 1, nh = w & 1;
  const int lan = l & 31, kgq = l >> 5;
  const int J = blockIdx.x;
  const int ny = blockIdx.y;
  const int n0 = ny * 64;

  const unsigned short* wsrc = W1p + (size_t)J * 65536 + (size_t)l * 8;
#pragma unroll
  for (int r = 0; r < 16; ++r) {
    int s = r * 8 + w;
    gll16(wsrc + (size_t)s * 512, Bs + s * 512);
  }

  const unsigned short* aH = hinH + (size_t)(ny * 2 + nh) * 16384 + l * 8;
  const unsigned short* aL = hinL + (size_t)(ny * 2 + nh) * 16384 + l * 8;

  f32x16 acc;
#pragma unroll
  for (int r = 0; r < 16; ++r) acc[r] = 0.f;

  __syncthreads();                         // drain gll16 + barrier

#pragma unroll
  for (int c = 0; c < 8; ++c) {
#pragma unroll
    for (int ks = 0; ks < 2; ++ks) {
      int cks = (kh * 8 + c) * 2 + ks;
      short8 ah = *(const short8*)(aH + (size_t)cks * 512);
      short8 al = *(const short8*)(aL + (size_t)cks * 512);
      int ub = (cks * 128 + kgq * 64 + jh * 32 + lan) * 8;
      short8 bh = *(const short8*)((const short*)Bs + ub);
      short8 bl = *(const short8*)((const short*)Bs + ub + 32768);
      acc = __builtin_amdgcn_mfma_f32_32x32x16_bf16(ah, bh, acc, 0, 0, 0);
      acc = __builtin_amdgcn_mfma_f32_32x32x16_bf16(ah, bl, acc, 0, 0, 0);
      acc = __builtin_amdgcn_mfma_f32_32x32x16_bf16(al, bh, acc, 0, 0, 0);
    }
  }

  __syncthreads();                         // Bs reads done -> safe to alias
  float* Gs = (float*)Bs;                  // [128 rows (kh,jl)][66]
#pragma unroll
  for (int r = 0; r < 16; ++r) {
    int nrow = (r & 3) + 8 * (r >> 2) + 4 * kgq;
    Gs[(kh * 64 + jh * 32 + lan) * 66 + nh * 32 + nrow] = acc[r];
  }
  __syncthreads();

  const int dl = tid & 15, q = tid >> 4;   // 16 d x 32 n-groups
  const int dg = J * 16 + dl;
  float wi[4], bsum[4];
#pragma unroll
  for (int g4 = 0; g4 < 4; ++g4) {
    int row = g4 * HD + dg;
    wi[g4] = Wih[row];
    bsum[g4] = bih[row] + bhh[row];
  }
#pragma unroll
  for (int s = 0; s < 2; ++s) {
    int nloc = q * 2 + s, n = n0 + nloc;
    float xv;
    if (t < TENC) xv = x[n * TENC + t];
    else {
      int j2 = t - TENC;
      xv = (tfm[j2] > 0) ? tgt[n * FDEC + j2] : outp[n * TTOT + t - 1];
    }
    float p[4];
#pragma unroll
    for (int g4 = 0; g4 < 4; ++g4)
      p[g4] = Gs[(dl * 4 + g4) * 66 + nloc] + Gs[(64 + dl * 4 + g4) * 66 + nloc]
            + xv * wi[g4] + bsum[g4];
    float ig = 1.f / (1.f + expf(-p[0]));
    float fg = 1.f / (1.f + expf(-p[1]));
    float gv = tanhf(p[2]);
    float og = 1.f / (1.f + expf(-p[3]));
    int idx = n * HD + dg;
    float c = fg * c1[idx] + ig * gv;
    c1[idx] = c;
    float h = og * tanhf(c);
    unsigned short hh = f2bf(h);
    size_t pi = hpk(n, dg);
    houtH[pi] = hh;
    houtL[pi] = f2bf(h - bf2f(hh));
  }
}

// ---------------------------------------------------------------------------
// Layer-2 step. Tile 32j x 128n, 8 waves = (kh K-half: h1|h2, nq n-quarter).
// Grid (64 J, 4 ny) = 256 blocks. Cell + packed h2 write + FC partial.
// ---------------------------------------------------------------------------
__global__ __launch_bounds__(512, 2) void lstm2_step(
    const unsigned short* __restrict__ a1H, const unsigned short* __restrict__ a1L,
    const unsigned short* __restrict__ a2H, const unsigned short* __restrict__ a2L,
    unsigned short* __restrict__ houtH, unsigned short* __restrict__ houtL,
    float* __restrict__ c2,
    const unsigned short* __restrict__ W2p,
    const float* __restrict__ bih, const float* __restrict__ bhh,
    const float* __restrict__ wfc, const float* __restrict__ bfc,
    float* __restrict__ outp, int t)
{
  __shared__ unsigned short Bs[65536];     // 128 KB; Gs/Rd alias after K-loop
  const int tid = threadIdx.x;
  const int w = tid >> 6, l = tid & 63;
  const int kh = w >> 2, nq = w & 3;
  const int lan = l & 31, kgq = l >> 5;
  const int J = blockIdx.x;
  const int ny = blockIdx.y;
  const int n0 = ny * 128;

  const unsigned short* wsrc = W2p + (size_t)J * 65536 + (size_t)l * 8;
#pragma unroll
  for (int r = 0; r < 16; ++r) {
    int s = r * 8 + w;
    gll16(wsrc + (size_t)s * 512, Bs + s * 512);
  }

  const unsigned short* aH = (kh ? a2H : a1H) + (size_t)(ny * 4 + nq) * 16384 + l * 8;
  const unsigned short* aL = (kh ? a2L : a1L) + (size_t)(ny * 4 + nq) * 16384 + l * 8;

  f32x16 acc;
#pragma unroll
  for (int r = 0; r < 16; ++r) acc[r] = 0.f;

  __syncthreads();

#pragma unroll
  for (int c = 0; c < 16; ++c) {
#pragma unroll
    for (int ks = 0; ks < 2; ++ks) {
      int cks = c * 2 + ks;                       // within this h buffer
      short8 ah = *(const short8*)(aH + (size_t)cks * 512);
      short8 al = *(const short8*)(aL + (size_t)cks * 512);
      int cksW = (kh * 16 + c) * 2 + ks;          // B k-index [0,64)
      int ub = (cksW * 64 + kgq * 32 + lan) * 8;
      short8 bh = *(const short8*)((const short*)Bs + ub);
      short8 bl = *(const short8*)((const short*)Bs + ub + 32768);
      acc = __builtin_amdgcn_mfma_f32_32x32x16_bf16(ah, bh, acc, 0, 0, 0);
      acc = __builtin_amdgcn_mfma_f32_32x32x16_bf16(ah, bl, acc, 0, 0, 0);
      acc = __builtin_amdgcn_mfma_f32_32x32x16_bf16(al, bh, acc, 0, 0, 0);
    }
  }

  __syncthreads();
  float* Gs = (float*)Bs;                  // [64 rows (kh,jl)][130]
  float* Rd = (float*)Bs + 64 * 130;       // [128][9]
#pragma unroll
  for (int r = 0; r < 16; ++r) {
    int nrow = (r & 3) + 8 * (r >> 2) + 4 * kgq;
    Gs[(kh * 32 + lan) * 130 + nq * 32 + nrow] = acc[r];
  }
  __syncthreads();

  const int dl = tid & 7, q = tid >> 3;    // 8 d x 64 n-groups
  const int dg = J * 8 + dl;
  float bsum[4];
#pragma unroll
  for (int g4 = 0; g4 < 4; ++g4) bsum[g4] = bih[g4 * HD + dg] + bhh[g4 * HD + dg];
  const float wf = wfc[dg];
#pragma unroll
  for (int s = 0; s < 2; ++s) {
    int nloc = q * 2 + s, n = n0 + nloc;
    float p[4];
#pragma unroll
    for (int g4 = 0; g4 < 4; ++g4)
      p[g4] = Gs[(dl * 4 + g4) * 130 + nloc] + Gs[(32 + dl * 4 + g4) * 130 + nloc]
            + bsum[g4];
    float ig = 1.f / (1.f + expf(-p[0]));
    float fg = 1.f / (1.f + expf(-p[1]));
    float gv = tanhf(p[2]);
    float og = 1.f / (1.f + expf(-p[3]));
    int idx = n * HD + dg;
    float c = fg * c2[idx] + ig * gv;
    c2[idx] = c;
    float h = og * tanhf(c);
    unsigned short hh = f2bf(h);
    size_t pi = hpk(n, dg);
    houtH[pi] = hh;
    houtL[pi] = f2bf(h - bf2f(hh));
    Rd[nloc * 9 + dl] = h * wf;
  }
  __syncthreads();
  if (tid < 128) {
    float sum = 0.f;
#pragma unroll
    for (int k = 0; k < 8; ++k) sum += Rd[tid * 9 + k];
    if (J == 0) sum += bfc[0];
    atomicAdd(&outp[(n0 + tid) * TTOT + t], sum);
  }
}

// ---------------------------------------------------------------------------
extern "C" void kernel_launch(void* const* d_in, const int* in_sizes, int n_in,
                              void* d_out, int out_size, void* d_ws, size_t ws_size,
                              hipStream_t stream)
{
  const float* x    = (const float*)d_in[0];
  const float* tgt  = (const float*)d_in[1];
  const int*   tfm  = (const int*)  d_in[2];
  const float* Wih1 = (const float*)d_in[4];
  const float* Whh1 = (const float*)d_in[5];
  const float* bih1 = (const float*)d_in[6];
  const float* bhh1 = (const float*)d_in[7];
  const float* Wih2 = (const float*)d_in[8];
  const float* Whh2 = (const float*)d_in[9];
  const float* bih2 = (const float*)d_in[10];
  const float* bhh2 = (const float*)d_in[11];
  const float* wfc  = (const float*)d_in[12];
  const float* bfc  = (const float*)d_in[13];
  float* outp = (float*)d_out;

  const size_t W1E = 32 * 65536;            // 4 MB
  const size_t W2E = 64 * 65536;            // 8 MB
  const size_t HE  = 512 * 512;
  unsigned short* W1p = (unsigned short*)d_ws;
  unsigned short* W2p = W1p + W1E;
  unsigned short* h1H = W2p + W2E;          // [2][HE] packed
  unsigned short* h1L = h1H + 2 * HE;
  unsigned short* h2H = h1L + 2 * HE;
  unsigned short* h2L = h2H + 2 * HE;
  float* c1 = (float*)(h2L + 2 * HE);
  float* c2 = c1 + HE;

  hipMemsetAsync(h1H, 0, 8 * HE * sizeof(unsigned short) + 2 * HE * sizeof(float), stream);
  hipMemsetAsync(d_out, 0, (size_t)NB * TTOT * sizeof(float), stream);

  split_w<<<1536, 256, 0, stream>>>(Whh1, Wih2, Whh2, W1p, W2p);

  dim3 g1(32, 8), g2(64, 4), blk(512);
  for (int t = 0; t < TTOT; ++t) {
    int p = t & 1;
    lstm1_step<<<g1, blk, 0, stream>>>(
        h1H + p * HE, h1L + p * HE, h1H + (p ^ 1) * HE, h1L + (p ^ 1) * HE,
        c1, W1p, Wih1, bih1, bhh1, x, tgt, tfm, outp, t);
    lstm2_step<<<g2, blk, 0, stream>>>(
        h1H + (p ^ 1) * HE, h1L + (p ^ 1) * HE, h2H + p * HE, h2L + p * HE,
        h2H + (p ^ 1) * HE, h2L + (p ^ 1) * HE,
        c2, W2p, bih2, bhh2, wfc, bfc, outp, t);
  }
}